// Round 1
// baseline (235.228 us; speedup 1.0000x reference)
//
#include <hip/hip_runtime.h>
#include <math.h>

// SPU transformer: pure elementwise, 32B read + 8B write per row, N=8.4M.
// R1: baseline float4 kernel, 101 us, HBM 1.96 TB/s, FETCH = 131 MB (2 of 4
//     inputs; L3 serves the rest), logical rate 3.3 TB/s.
// R4: NT store + 2 float4/thread (regular loads): 110 us (worse).
// R5 (current best): NT loads on ALL streams -> 59.2 us/dispatch. FETCH still
//     exactly 128 MiB (= 2 of 4 input streams; inputs exactly fill the 256 MiB
//     L3), WRITE exactly 64 MiB. Logical BW = 401 MB / 59.2 us = 6.8 TB/s
//     (above the 6.29 TB/s copy ceiling -- L3 hits are cheaper than HBM).
// R6 (this round): disambiguate fabric-bound vs latency-bound. VALUBusy 32%,
//     MfmaUtil 0, Occupancy 66%, HBM physical only 54% of achievable ->
//     nothing is saturated, consistent with un-hidden L3/HBM latency.
//     Change (single variable): 2 float4/thread per stream with BLOCK-granular
//     unroll (thread handles quad base and base+256) so every load instruction
//     remains a perfectly-coalesced 1 KiB wave access; all 8 loads issued
//     before first use. R4's failure mode predated the NT-load regime.
// Predicted: FETCH/WRITE unchanged. Latency model: dur -> 48-52 us.
//     Fabric model: neutral ~59 us (=> declare roofline next round).

typedef float nfloat4 __attribute__((ext_vector_type(4)));

__device__ __forceinline__ float spu_f(float x) {
    // x >= 0: x*x - 0.5 ; x < 0: sigmoid(-x) - 1 = 1/(1+e^x) - 1
    if (x >= 0.0f) {
        return x * x - 0.5f;
    } else {
        return 1.0f / (1.0f + __expf(x)) - 1.0f;
    }
}

__device__ __forceinline__ void spu_row(float l, float u,
                                        float p1l, float p1u,
                                        float q1l, float q1u,
                                        float b0l, float b0u,
                                        float& out_lo, float& out_hi) {
    const float sl = spu_f(l);
    const float su = spu_f(u);

    const bool neg   = (u <= 0.0f);
    const bool pos   = (l >= 0.0f);
    const bool cross = !(neg || pos);

    const float all_slopes = (su - sl) / (u - l);

    const float s0 = neg ? all_slopes : 0.0f;
    const float s1 = (pos || cross) ? all_slopes : 0.0f;

    const bool neg_slope = (all_slopes < 0.0f);
    float lo = neg_slope ? su : sl;
    float hi = neg_slope ? sl : su;
    lo = cross ? -0.5f : lo;

    float sh1 = fmaf(-s1, u, su);  // su - s1*u
    float sh0 = fmaf(-s0, l, sl);  // sl - s0*l
    sh0 = cross ? -0.5f : sh0;
    sh1 = neg ? sl : sh1;

    const float s1p = fmaxf(s1, 0.0f), s1n = fminf(s1, 0.0f);
    const float s0p = fmaxf(s0, 0.0f), s0n = fminf(s0, 0.0f);

    const float UBM = s1p * p1u + s1n * p1l;
    const float UBV = s1p * q1u + sh1 + s1n * q1l;
    const float LBM = s0p * p1l + s0n * p1u;
    const float LBV = s0n * q1l + sh0 + s0p * q1u;

    const float lower = fmaxf(LBM, 0.0f) * b0l + fminf(LBM, 0.0f) * b0u + LBV;
    const float upper = fmaxf(UBM, 0.0f) * b0u + fminf(UBM, 0.0f) * b0l + UBV;

    out_lo = (lower > lo) ? lower : lo;
    out_hi = (upper < hi) ? upper : hi;
}

__device__ __forceinline__ nfloat4 spu_quad(const nfloat4 b, const nfloat4 sp,
                                            const nfloat4 sh, const nfloat4 bp) {
    float o0, o1, o2, o3;
    spu_row(b.x, b.y, sp.x, sp.y, sh.x, sh.y, bp.x, bp.y, o0, o1);
    spu_row(b.z, b.w, sp.z, sp.w, sh.z, sh.w, bp.z, bp.w, o2, o3);
    nfloat4 o;
    o.x = o0; o.y = o1; o.z = o2; o.w = o3;
    return o;
}

__global__ __launch_bounds__(256) void SPUTransformer_62002147885333_kernel(
    const nfloat4* __restrict__ bounds,
    const nfloat4* __restrict__ slopes_prev,
    const nfloat4* __restrict__ shifts_prev,
    const nfloat4* __restrict__ bounds_prev,
    nfloat4* __restrict__ out,
    int nquads)  // nquads = N/2; one float4 = two (l,u) rows
{
    // Block-granular 2x unroll: block b owns quads [b*512, b*512+512).
    // Lane t handles quad b*512+t and b*512+256+t -> every load instruction
    // is a fully-coalesced, contiguous 1 KiB wave access.
    const int base = blockIdx.x * (blockDim.x * 2) + threadIdx.x;
    const int i0 = base;
    const int i1 = base + blockDim.x;

    if (i1 < nquads) {
        // Issue all 8 streaming loads before any use: 8 KiB in flight per
        // thread-pair of quads, 2x the previous MLP.
        const nfloat4 b0  = __builtin_nontemporal_load(&bounds[i0]);
        const nfloat4 b1  = __builtin_nontemporal_load(&bounds[i1]);
        const nfloat4 sp0 = __builtin_nontemporal_load(&slopes_prev[i0]);
        const nfloat4 sp1 = __builtin_nontemporal_load(&slopes_prev[i1]);
        const nfloat4 sh0 = __builtin_nontemporal_load(&shifts_prev[i0]);
        const nfloat4 sh1 = __builtin_nontemporal_load(&shifts_prev[i1]);
        const nfloat4 bp0 = __builtin_nontemporal_load(&bounds_prev[i0]);
        const nfloat4 bp1 = __builtin_nontemporal_load(&bounds_prev[i1]);

        const nfloat4 o0 = spu_quad(b0, sp0, sh0, bp0);
        const nfloat4 o1 = spu_quad(b1, sp1, sh1, bp1);

        __builtin_nontemporal_store(o0, &out[i0]);
        __builtin_nontemporal_store(o1, &out[i1]);
    } else if (i0 < nquads) {
        // Tail (not hit for N=8388608, kept for generality).
        const nfloat4 b  = __builtin_nontemporal_load(&bounds[i0]);
        const nfloat4 sp = __builtin_nontemporal_load(&slopes_prev[i0]);
        const nfloat4 sh = __builtin_nontemporal_load(&shifts_prev[i0]);
        const nfloat4 bp = __builtin_nontemporal_load(&bounds_prev[i0]);
        const nfloat4 o  = spu_quad(b, sp, sh, bp);
        __builtin_nontemporal_store(o, &out[i0]);
    }
}

extern "C" void kernel_launch(void* const* d_in, const int* in_sizes, int n_in,
                              void* d_out, int out_size, void* d_ws, size_t ws_size,
                              hipStream_t stream) {
    // Inputs (setup_inputs order): bounds (N,2), slopes_prev (N,2),
    // shifts_prev (N,2), bounds_prev (N,2) -- all float32.
    const nfloat4* bounds      = (const nfloat4*)d_in[0];
    const nfloat4* slopes_prev = (const nfloat4*)d_in[1];
    const nfloat4* shifts_prev = (const nfloat4*)d_in[2];
    const nfloat4* bounds_prev = (const nfloat4*)d_in[3];
    nfloat4* out = (nfloat4*)d_out;

    const int n_rows = in_sizes[0] / 2;   // N
    const int nquads = n_rows / 2;        // N even (8388608)

    const int block = 256;
    const int quads_per_block = block * 2;
    const int grid = (nquads + quads_per_block - 1) / quads_per_block;

    SPUTransformer_62002147885333_kernel<<<grid, block, 0, stream>>>(
        bounds, slopes_prev, shifts_prev, bounds_prev, out, nquads);
}